// Round 8
// baseline (9178.233 us; speedup 1.0000x reference)
//
#include <hip/hip_runtime.h>

#define Hdim 64
#define Tlen 16384
#define Bsz  16
#define LOG2E 1.44269504088896340736f

// readlane: broadcast lane l's value of v to an SGPR (uniform)
__device__ __forceinline__ float rlane(float v, int l) {
    return __int_as_float(__builtin_amdgcn_readlane(__float_as_int(v), l));
}

// sigmoid(x) = 1/(1+2^(-x*log2e))   : v_mul, v_exp, v_add, v_rcp
__device__ __forceinline__ float sigm(float x) {
    return __builtin_amdgcn_rcpf(1.0f + __builtin_amdgcn_exp2f(-LOG2E * x));
}
// tanh(x) = 1 - 2/(2^(2x*log2e)+1)  : saturates correctly at +/-1
__device__ __forceinline__ float tanhfast(float x) {
    const float e = __builtin_amdgcn_exp2f((2.0f * LOG2E) * x);
    return fmaf(-2.0f, __builtin_amdgcn_rcpf(e + 1.0f), 1.0f);
}

__global__ void __launch_bounds__(256, 1)
apdl_rnn_kernel(const float* __restrict__ x,
                const float* __restrict__ W_ih,
                const float* __restrict__ W_hh,
                const float* __restrict__ b_ih,
                const float* __restrict__ b_hh,
                float* __restrict__ out)
{
    const int b    = blockIdx.x;   // batch element
    const int tid  = threadIdx.x;  // 0..255 == gate-row index
    const int wid  = tid >> 6;     // wave id: 0=i, 1=f, 2=g, 3=o gates
    const int lane = tid & 63;     // j index within hidden dim

    // W_hh row residency, attempt 4 (r3: remat'd; r4: spilled to scratch;
    // r5: remat'd; r7: compile fail on tied float4 asm operands).
    // The loads are OPAQUE VOLATILE ASM defs: not rematerializable, not
    // re-executable. No in-loop asm ties (r4's mistake). The wait has NO
    // tied operands (r7's compile failure); ordering is guaranteed by
    // volatile-asm program order + sched_barrier(0) + the loop-body BB
    // being dominated by this preheader.
    const float* wp = W_hh + (size_t)tid * Hdim;
    float4 wv[16];
    #pragma unroll
    for (int i = 0; i < 16; ++i) {
        asm volatile("global_load_dwordx4 %0, %1, off offset:%2"
                     : "=v"(wv[i])
                     : "v"(wp), "i"(16 * i));
    }
    asm volatile("s_waitcnt vmcnt(0)" ::: "memory");
    __builtin_amdgcn_sched_barrier(0);     // rule-#18 fence

    const float bias = b_ih[tid] + b_hh[tid];
    const float wih  = W_ih[tid];          // I == 1

    // ap_coeff = (1-alpha)/(1+alpha), alpha = 48000/44100-1  ->  exactly 0.8375
    const float apc = 0.8375f;

    // State, replicated per wave; lane j holds index j of each vector.
    float ap_h = 0.f, ap_c = 0.f;          // allpass output (LSTM h,c input)
    float h1 = 0.f, c1 = 0.f;              // hc_{t-1}
    float h2 = 0.f, c2 = 0.f;              // hc_{t-2}

    __shared__ float gbuf[2][256];         // double-buffered activated gates
    __shared__ float apbuf[4][Hdim];       // per-wave private h-broadcast buf

    const float* xb = x + (size_t)b * Tlen;
    float xnext = xb[lane];                // prefetch first 64 timesteps
    float xcur  = 0.f;

    float* yp = out + (size_t)b * Tlen * Hdim + lane;
    float* cp = out + (size_t)Bsz * Tlen * Hdim + (size_t)b * Tlen * Hdim + lane;

    float* apw = &apbuf[wid][0];

    for (int t = 0; t < Tlen; ++t) {
        if ((t & 63) == 0) {               // uniform branch, once per 64 steps
            xcur = xnext;
            if (t + 64 < Tlen) xnext = xb[t + 64 + lane];
        }
        const float xt = rlane(xcur, t & 63);

        // allpass filter: ap_t = apc*(hc_{t-1} - ap_{t-1}) + hc_{t-2}
        ap_h = fmaf(apc, h1 - ap_h, h2);
        ap_c = fmaf(apc, c1 - ap_c, c2);

        // Broadcast ap_h across the wave through this wave's private LDS
        // buffer: 1 ds_write + 16 uniform-address ds_read_b128 (broadcast,
        // conflict-free, same-wave RAW -> no barrier needed).
        apw[lane] = ap_h;

        float a0 = fmaf(xt, wih, bias);
        float a1 = 0.f, a2 = 0.f, a3 = 0.f;
        const float4* hp = reinterpret_cast<const float4*>(apw);
        #pragma unroll
        for (int k4 = 0; k4 < Hdim / 4; ++k4) {
            const float4 hv = hp[k4];
            a0 = fmaf(hv.x, wv[k4].x, a0);
            a1 = fmaf(hv.y, wv[k4].y, a1);
            a2 = fmaf(hv.z, wv[k4].z, a2);
            a3 = fmaf(hv.w, wv[k4].w, a3);
        }
        const float gate = (a0 + a1) + (a2 + a3);

        // activation: wave-uniform branch (wave 2 = cell gate = tanh)
        float act;
        if (wid == 2) act = tanhfast(gate);
        else          act = sigm(gate);

        gbuf[t & 1][tid] = act;
        __syncthreads();                   // single barrier per step (dbuf'd)

        const float* gb = gbuf[t & 1];
        const float ig = gb[lane];
        const float fg = gb[64  + lane];
        const float gg = gb[128 + lane];
        const float og = gb[192 + lane];

        // epilogue, redundantly on all 4 waves to keep state replicated
        const float cn = fmaf(fg, ap_c, ig * gg);
        const float hn = og * tanhfast(cn);

        h2 = h1; c2 = c1; h1 = hn; c1 = cn;

        if      (wid == 0) *yp = hn;       // y output
        else if (wid == 1) *cp = cn;       // c output
        yp += Hdim; cp += Hdim;
    }

    // ap_final: the ap used as input to the last cell (B, 2H)
    if (wid == 0) {
        float* ap_out = out + 2 * (size_t)Bsz * Tlen * Hdim + (size_t)b * 2 * Hdim;
        ap_out[lane]        = ap_h;
        ap_out[Hdim + lane] = ap_c;
    }
}

extern "C" void kernel_launch(void* const* d_in, const int* in_sizes, int n_in,
                              void* d_out, int out_size, void* d_ws, size_t ws_size,
                              hipStream_t stream) {
    const float* x    = (const float*)d_in[0];
    const float* W_ih = (const float*)d_in[1];
    const float* W_hh = (const float*)d_in[2];
    const float* b_ih = (const float*)d_in[3];
    const float* b_hh = (const float*)d_in[4];
    float* out = (float*)d_out;

    apdl_rnn_kernel<<<dim3(Bsz), dim3(256), 0, stream>>>(x, W_ih, W_hh, b_ih, b_hh, out);
}

// Round 9
// 8834.327 us; speedup vs baseline: 1.0389x; 1.0389x over previous
//
#include <hip/hip_runtime.h>

#define Hdim 64
#define Tlen 16384
#define Bsz  16
#define LOG2E 1.44269504088896340736f

typedef _Float16 half8 __attribute__((ext_vector_type(8)));
typedef float    f32x4 __attribute__((ext_vector_type(4)));

__device__ __forceinline__ float sigm(float x) {
    return __builtin_amdgcn_rcpf(1.0f + __builtin_amdgcn_exp2f(-LOG2E * x));
}
__device__ __forceinline__ float tanhfast(float x) {
    const float e = __builtin_amdgcn_exp2f((2.0f * LOG2E) * x);
    return fmaf(-2.0f, __builtin_amdgcn_rcpf(e + 1.0f), 1.0f);
}

__global__ void __launch_bounds__(256)
__attribute__((amdgpu_waves_per_eu(1, 1)))
apdl_rnn_mfma(const float* __restrict__ x,
              const float* __restrict__ W_ih,
              const float* __restrict__ W_hh,
              const float* __restrict__ b_ih,
              const float* __restrict__ b_hh,
              float* __restrict__ out)
{
    // LDS: W frags 32KB + ap dbuf 4KB + x dbuf 8KB + bias/wih 2KB ~= 46KB
    __shared__ _Float16 wfrag[16 * 2 * 64 * 8];
    __shared__ char     apraw[2][2048];
    __shared__ float    xbuf[2][64][16];
    __shared__ float    bias_lds[256];
    __shared__ float    wih_lds[256];

    const int tid = threadIdx.x;
    const int w   = tid >> 6;       // wave id: owns j-slice [w*16, w*16+16) of ALL 4 gates
    const int l   = tid & 63;
    const int b   = l & 15;         // batch (MFMA N / C-col)
    const int g16 = l >> 4;
    const int j0  = w * 16 + g16 * 4;  // this lane's 4 hidden indices j0..j0+3

    bias_lds[tid] = b_ih[tid] + b_hh[tid];
    wih_lds[tid]  = W_ih[tid];      // I == 1

    // ---- pack W_hh into MFMA A-fragment order (f16) ----
    // tile T (16 rows of G^T), chunk c (K 32-slice); lane vl holds
    // A[row=vl&15][k=(vl>>4)*8 + 0..8] stored lane-contiguous (conflict-free b128).
    {
        const int T = tid >> 4, s = tid & 15;
        #pragma unroll
        for (int q = 0; q < 4; ++q) {
            const int vl  = s * 4 + q;
            const int row = T * 16 + (vl & 15);
            #pragma unroll
            for (int c = 0; c < 2; ++c) {
                const int kb = c * 32 + (vl >> 4) * 8;
                half8 tmp;
                #pragma unroll
                for (int i = 0; i < 8; ++i)
                    tmp[i] = (_Float16)W_hh[row * 64 + kb + i];
                *(half8*)&wfrag[((T * 2 + c) * 64 + vl) * 8] = tmp;
            }
        }
    }
    __syncthreads();

    // Hoist loop-invariant operands to regs (LDS remains as cheap remat backing)
    half8 af[4][2];                 // W frags: gate g, K-chunk c (tile = g*4+w)
    f32x4 bias4[4], wih4[4];
    #pragma unroll
    for (int g = 0; g < 4; ++g) {
        #pragma unroll
        for (int c = 0; c < 2; ++c)
            af[g][c] = *(const half8*)&wfrag[(g * 8 + w * 2 + c) * 512 + l * 8];
        bias4[g] = *(const f32x4*)&bias_lds[g * 64 + j0];
        wih4[g]  = *(const f32x4*)&wih_lds[g * 64 + j0];
    }

    // ap tile addressing: row b (128B), XOR-swizzle bits 4..6 with b&7
    // (kills the stride-128B same-bank pattern on both write and read sides).
    const int swz     = (b & 7) << 4;
    const int wr_off  = b * 128 + ((w * 32 + g16 * 8) ^ swz);   // 8B write: (b, j0..j0+3)
    const int rd0_off = b * 128 + ((g16 * 16) ^ swz);           // 16B read: (b, g16*8 + 0..8)
    const int rd1_off = b * 128 + ((64 + g16 * 16) ^ swz);      // 16B read: +32 j

    const float apcK = 0.8375f;     // (1-alpha)/(1+alpha) exactly
    f32x4 aph = {0,0,0,0}, apcv = {0,0,0,0};
    f32x4 h1v = {0,0,0,0}, c1v = {0,0,0,0};
    f32x4 h2v = {0,0,0,0}, c2v = {0,0,0,0};

    float* yp = out + (size_t)b * Tlen * Hdim + j0;
    float* cp = yp + (size_t)Bsz * Tlen * Hdim;

    const int st_b = tid >> 4;          // x staging: batch
    const int st_t = (tid & 15) * 4;    // x staging: t offset

    auto step = [&](int t, int par, f32x4& h_prev, f32x4& c_prev,
                    f32x4& h_prev2, f32x4& c_prev2) {
        // stage x[t..t+64) (transposed) once per 64 steps; pre-barrier (safe:
        // racing wave is blocked by the barrier chain; x dbuf by (t>>6)&1)
        if ((t & 63) == 0) {
            const int buf = (t >> 6) & 1;
            const float4 xv = *(const float4*)&x[(size_t)st_b * Tlen + t + st_t];
            xbuf[buf][st_t + 0][st_b] = xv.x;
            xbuf[buf][st_t + 1][st_b] = xv.y;
            xbuf[buf][st_t + 2][st_b] = xv.z;
            xbuf[buf][st_t + 3][st_b] = xv.w;
        }
        // allpass: ap_t = apc*(hc_{t-1} - ap_{t-1}) + hc_{t-2}   (lane-local)
        #pragma unroll
        for (int r = 0; r < 4; ++r) {
            aph[r]  = fmaf(apcK, h_prev[r] - aph[r],  h_prev2[r]);
            apcv[r] = fmaf(apcK, c_prev[r] - apcv[r], c_prev2[r]);
        }
        // publish ap_h (f16) for everyone's B-fragment
        union { _Float16 h[4]; uint2 u; } pk;
        #pragma unroll
        for (int r = 0; r < 4; ++r) pk.h[r] = (_Float16)aph[r];
        *(uint2*)(apraw[par] + wr_off) = pk.u;

        __syncthreads();               // single barrier per step (ap dbuf'd)

        const float xv  = xbuf[(t >> 6) & 1][t & 63][b];
        const half8 bf0 = *(const half8*)(apraw[par] + rd0_off);
        const half8 bf1 = *(const half8*)(apraw[par] + rd1_off);

        // G^T tiles: acc[g][r] = gate g, row j0+r, batch b
        f32x4 acc[4];
        #pragma unroll
        for (int g = 0; g < 4; ++g) {
            f32x4 ci;
            #pragma unroll
            for (int r = 0; r < 4; ++r) ci[r] = fmaf(xv, wih4[g][r], bias4[g][r]);
            ci     = __builtin_amdgcn_mfma_f32_16x16x32_f16(af[g][0], bf0, ci, 0, 0, 0);
            acc[g] = __builtin_amdgcn_mfma_f32_16x16x32_f16(af[g][1], bf1, ci, 0, 0, 0);
        }

        // epilogue fully in-register: this lane owns i,f,g,o of its 4 elems
        f32x4 hn, cn;
        #pragma unroll
        for (int r = 0; r < 4; ++r) {
            const float ig = sigm(acc[0][r]);
            const float fg = sigm(acc[1][r]);
            const float gg = tanhfast(acc[2][r]);
            const float og = sigm(acc[3][r]);
            cn[r] = fmaf(fg, apcv[r], ig * gg);
            hn[r] = og * tanhfast(cn[r]);
        }
        *(f32x4*)yp = hn;
        *(f32x4*)cp = cn;
        yp += Hdim; cp += Hdim;
        h_prev2 = hn; c_prev2 = cn;    // caller's swap renames states
    };

    for (int t = 0; t < Tlen; t += 2) {
        step(t,     0, h1v, c1v, h2v, c2v);   // writes h_t   into h2v
        step(t + 1, 1, h2v, c2v, h1v, c1v);   // writes h_t+1 into h1v
    }

    // ap_final = ap used by the last cell (B, 2H)
    float* apf = out + 2 * (size_t)Bsz * Tlen * Hdim + (size_t)b * 2 * Hdim + j0;
    *(f32x4*)apf          = aph;
    *(f32x4*)(apf + Hdim) = apcv;
}

extern "C" void kernel_launch(void* const* d_in, const int* in_sizes, int n_in,
                              void* d_out, int out_size, void* d_ws, size_t ws_size,
                              hipStream_t stream) {
    const float* x    = (const float*)d_in[0];
    const float* W_ih = (const float*)d_in[1];
    const float* W_hh = (const float*)d_in[2];
    const float* b_ih = (const float*)d_in[3];
    const float* b_hh = (const float*)d_in[4];
    float* out = (float*)d_out;

    apdl_rnn_mfma<<<dim3(1), dim3(256), 0, stream>>>(x, W_ih, W_hh, b_ih, b_hh, out);
}